// Round 5
// baseline (436.421 us; speedup 1.0000x reference)
//
#include <hip/hip_runtime.h>
#include <hip/hip_bf16.h>
#include <math.h>

// ---------------------------------------------------------------------------
// DIM=256 HEADS=16 DHEAD=16 H=12 W=26 (HW=312)  Hk=3 Wk=6 (J=18)  B=256
// q_map[b,c,s] = q[b,(c*56+s)&255]
// Round 12: 3-kernel split for occupancy. r9-r11 evidence: blocks >512 thr
// get allocator-shrunk VGPR targets (64/84) + spill; 512-thr shape (r7) is
// the proven clean codegen (120 regs). Grid 256 = 1 block/CU caps r7 at
// 8 waves/CU. Fix: more BLOCKS, not bigger blocks.
//   k_setup  grid 256: r7 setup verbatim; exports q^,k,v bf16 + n0/n1 to ws
//   k_chunks grid 512 (b,g): half the i-range per block, 10 chunks of 16 i;
//            LDS 62KB -> 2 blocks/CU = 16 waves/CU; LB(512,4) caps 128 regs
//            (demand ~100: w1p in LDS, lv/wAcc 9-half-split, no setup code)
//   k_tail   grid 256: wA halves -> m -> pooled -> residual+LN
// ws usage ~5.5 MB. Softmax rows independent per i -> split is exact.
// ---------------------------------------------------------------------------

typedef __attribute__((ext_vector_type(8))) short short8;   // 8 bf16
typedef __attribute__((ext_vector_type(4))) float floatx4;

union U16 { uint4 u; short8 s; };

#define MFMA(A, B, C) __builtin_amdgcn_mfma_f32_16x16x32_bf16((A), (B), (C), 0, 0, 0)

__device__ __forceinline__ unsigned int f2bf(float f) {   // RNE f32->bf16 (low 16)
    unsigned int u = __float_as_uint(f);
    u += 0x7fffu + ((u >> 16) & 1u);
    return u >> 16;
}
__device__ __forceinline__ unsigned int pk2(float a, float b) {   // HW cvt_pk
    __hip_bfloat162 h = __float22bfloat162_rn(make_float2(a, b));
    union { __hip_bfloat162 h; unsigned int u; } cv; cv.h = h;
    return cv.u;
}
__device__ __forceinline__ float bf2f(unsigned short v) {
    return __uint_as_float((unsigned int)v << 16);
}
__device__ __forceinline__ uint4 pack8(float4 a, float4 b) {
    uint4 r;
    r.x = pk2(a.x, a.y); r.y = pk2(a.z, a.w);
    r.z = pk2(b.x, b.y); r.w = pk2(b.z, b.w);
    return r;
}

// ===========================================================================
// Kernel 1: setup (r7-verbatim phases) + export to workspace
// ===========================================================================
__global__ __launch_bounds__(512, 2) void k_setup(
    const float* __restrict__ x, const float* __restrict__ q,
    const float* __restrict__ w_dw, const float* __restrict__ b_dw,
    const float* __restrict__ w_pw,
    const float* __restrict__ wk, const float* __restrict__ wv,
    unsigned short* __restrict__ ws_q, unsigned short* __restrict__ ws_k,
    unsigned short* __restrict__ ws_v, float* __restrict__ ws_n01)
{
    const int b = blockIdx.x, tid = threadIdx.x;
    const int w = tid >> 6, lane = tid & 63;
    const int n = lane & 15, qd = lane >> 4;

    __shared__ unsigned short q_sb[256];
    __shared__ unsigned short v_sb[5120];           // [256][20]
    __shared__ float off_s[36], n0_s[18], n1_s[18];
    __shared__ float sx0[18], sy0[18], swx[18], swy[18];
    __shared__ float t_red[36];
    __shared__ __align__(16) unsigned char UB[34944];
    float* qsw = (float*)UB;                         // 4128 f (16 x 258)
    unsigned short* kvT = (unsigned short*)UB;       // [18][264] aliases qsw
    float* t_s = (float*)(UB + 16512);               // [18][256]
    unsigned short* k_sb = (unsigned short*)(UB + 16512);  // [256][20] aliases t_s

    // ---- stage 0 ----
    if (tid < 256) {
        const float qv = q[b * 256 + tid];
        const unsigned short qb = (unsigned short)f2bf(qv * 0.25f);
        q_sb[tid] = qb;
        ws_q[b * 256 + tid] = qb;
    }
    for (int u = tid; u < 4128; u += 512) {
        const int r = u / 258, i = u - r * 258;
        qsw[u] = (i < 256) ? q[b * 256 + i] : 0.f;
    }
    __syncthreads();

    // ---- depthwise conv 6x6 s4 p1 + GELU -> t_s ----
    {
        const int c = tid & 255, g = tid >> 8;     // g: jw-half
        float wreg[36];
        const float4* wdw4 = (const float4*)w_dw;  // [c][36] contiguous
        #pragma unroll
        for (int i = 0; i < 9; ++i) {
            const float4 t4 = wdw4[c * 9 + i];
            wreg[i * 4 + 0] = t4.x; wreg[i * 4 + 1] = t4.y;
            wreg[i * 4 + 2] = t4.z; wreg[i * 4 + 3] = t4.w;
        }
        float acc[9];
        const float bv = b_dw[c];
        #pragma unroll
        for (int a = 0; a < 9; ++a) acc[a] = bv;
        const int cb = (c * 56) & 255;
        const int cp = (c & 15) * 258;
        for (int jh = 0; jh < 3; ++jh) {
            for (int kh = 0; kh < 6; ++kh) {
                const int ih = jh * 4 - 1 + kh;
                if (ih < 0 || ih >= 12) continue;
                const int rb = ih * 26;
                #pragma unroll
                for (int jwl = 0; jwl < 3; ++jwl) {
                    const int jw = g * 3 + jwl;
                    #pragma unroll
                    for (int kw = 0; kw < 6; ++kw) {
                        const int iw = jw * 4 - 1 + kw;
                        if (iw < 0 || iw >= 26) continue;
                        acc[jh * 3 + jwl] += wreg[kh * 6 + kw] * qsw[cp + ((cb + rb + iw) & 255)];
                    }
                }
            }
        }
        #pragma unroll
        for (int a = 0; a < 9; ++a) {
            const int jh = a / 3, jwl = a - jh * 3;
            const int p = jh * 6 + g * 3 + jwl;
            const float v = acc[a];
            t_s[p * 256 + c] = 0.5f * v * (1.0f + erff(v * 0.70710678118654752f));
        }
    }
    __syncthreads();

    // ---- offsets: 36 dots over 256 channels ----
    for (int oi = w; oi < 36; oi += 8) {
        const int o = oi / 18, p = oi - o * 18;
        float s = 0.f;
        for (int c = lane; c < 256; c += 64) s += w_pw[o * 256 + c] * t_s[p * 256 + c];
        for (int d = 32; d > 0; d >>= 1) s += __shfl_down(s, d, 64);
        if (lane == 0) off_s[oi] = 4.0f * tanhf(s);
    }
    (void)t_red;
    __syncthreads();

    // ---- grid coords + bilinear params (+ n0/n1 export) ----
    if (tid < 18) {
        const int j = tid, jh = j / 6, jw = j - jh * 6;
        const float vg0 = (float)jw + off_s[j];
        const float vg1 = (float)jh + off_s[18 + j];
        const float n0 = 2.0f * vg0 / 2.0f - 1.0f;
        const float n1 = 2.0f * vg1 / 5.0f - 1.0f;
        n0_s[j] = n0; n1_s[j] = n1;
        ws_n01[b * 36 + j] = n0;
        ws_n01[b * 36 + 18 + j] = n1;
        const float xp = ((n0 + 1.0f) * 26.0f - 1.0f) * 0.5f;
        const float yp = ((n1 + 1.0f) * 12.0f - 1.0f) * 0.5f;
        const float x0 = floorf(xp), y0 = floorf(yp);
        sx0[j] = x0; sy0[j] = y0; swx[j] = xp - x0; swy[j] = yp - y0;
    }
    __syncthreads();

    // ---- bilinear sample -> kvT bf16 [j][264] (qsw region dead) ----
    {
        const int c = tid & 255, g = tid >> 8;
        const float* xb = x + ((size_t)b * 256 + c) * 312;
        for (int jj = 0; jj < 9; ++jj) {
            const int j = g * 9 + jj;
            const int x0 = (int)sx0[j], y0 = (int)sy0[j];
            const int x1 = x0 + 1, y1 = y0 + 1;
            const float wx1 = swx[j], wy1 = swy[j];
            const float wx0 = 1.f - wx1, wy0 = 1.f - wy1;
            const bool xv0 = (x0 >= 0) & (x0 < 26), xv1 = (x1 >= 0) & (x1 < 26);
            const bool yv0 = (y0 >= 0) & (y0 < 12), yv1 = (y1 >= 0) & (y1 < 12);
            const float v00 = (xv0 & yv0) ? xb[y0 * 26 + x0] : 0.f;
            const float v01 = (xv1 & yv0) ? xb[y0 * 26 + x1] : 0.f;
            const float v10 = (xv0 & yv1) ? xb[y1 * 26 + x0] : 0.f;
            const float v11 = (xv1 & yv1) ? xb[y1 * 26 + x1] : 0.f;
            const float val = wy0 * (wx0 * v00 + wx1 * v01) + wy1 * (wx0 * v10 + wx1 * v11);
            kvT[j * 264 + c] = (unsigned short)f2bf(val);
        }
    }
    __syncthreads();

    // ---- k/v projection via MFMA: wave w -> matrix (w&1), mtb = w>>1 ----
    {
        const int m2 = w & 1, mtb = w >> 1;
        const float4* wm4 = (const float4*)(m2 ? wv : wk);
        floatx4 pa[4][2];
        #pragma unroll
        for (int a = 0; a < 4; ++a) {
            pa[a][0] = (floatx4){0.f, 0.f, 0.f, 0.f};
            pa[a][1] = (floatx4){0.f, 0.f, 0.f, 0.f};
        }
        #pragma unroll 2
        for (int ks = 0; ks < 8; ++ks) {
            U16 b0, b1;
            b0.u = *(const uint4*)(kvT + n * 264 + ks * 32 + qd * 8);
            b1.u = make_uint4(0u, 0u, 0u, 0u);
            if (n < 2) b1.u = *(const uint4*)(kvT + (16 + n) * 264 + ks * 32 + qd * 8);
            #pragma unroll
            for (int mtl = 0; mtl < 4; ++mtl) {
                const int mt = mtb + mtl * 4;
                const int f4i = (mt * 16 + n) * 64 + ks * 8 + qd * 2;
                U16 A; A.u = pack8(wm4[f4i], wm4[f4i + 1]);
                pa[mtl][0] = MFMA(A.s, b0.s, pa[mtl][0]);
                pa[mtl][1] = MFMA(A.s, b1.s, pa[mtl][1]);
            }
        }
        unsigned short* dst = m2 ? v_sb : k_sb;
        #pragma unroll
        for (int mtl = 0; mtl < 4; ++mtl) {
            const int mt = mtb + mtl * 4;
            #pragma unroll
            for (int r = 0; r < 4; ++r) {
                const int o = mt * 16 + qd * 4 + r;
                dst[o * 20 + n] = (unsigned short)f2bf(pa[mtl][0][r]);
                if (n < 2) dst[o * 20 + 16 + n] = (unsigned short)f2bf(pa[mtl][1][r]);
            }
        }
    }
    __syncthreads();

    // ---- export k, v as [256][18] bf16 ----
    for (int u = tid; u < 4608; u += 512) {
        const int c = u / 18, j = u - c * 18;
        ws_k[b * 4608 + u] = k_sb[c * 20 + j];
        ws_v[b * 4608 + u] = v_sb[c * 20 + j];
    }
}

// ===========================================================================
// Kernel 2: chunk loop. Block (b,g): i in [g*156, g*156+156), 10 chunks of 16
// ===========================================================================
__global__ __launch_bounds__(512, 4) void k_chunks(
    const float* __restrict__ cw1, const float* __restrict__ cb1,
    const float* __restrict__ cw2, const float* __restrict__ cb2,
    const float* __restrict__ cw3, const float* __restrict__ cb3,
    const float* __restrict__ conv_w,
    const unsigned short* __restrict__ ws_q, const unsigned short* __restrict__ ws_k,
    const float* __restrict__ ws_n01, float* __restrict__ ws_wa)
{
    const int bb = blockIdx.x;                     // 0..511
    const int b = bb >> 1, g = bb & 1;
    const int tid = threadIdx.x;
    const int w = tid >> 6, lane = tid & 63;       // w in 0..7
    const int n = lane & 15, qd = lane >> 4;

    __shared__ unsigned short q_sb[256];
    __shared__ float F0[468], F1[216];
    __shared__ float n0_s[18], n1_s[18];
    __shared__ unsigned int lutxy[312];
    __shared__ float b2_s[64], b3_s[16];
    __shared__ __align__(16) float w1p[4][8][8];
    // S double buffer 2 x [16 il][18 j][17 h] f32 = 39168 B; h2w 8x544 uints
    __shared__ __align__(16) unsigned char UB[56576];
    float* Sbuf = (float*)UB;
    unsigned int* h2w = (unsigned int*)(UB + 39168);
    float* wred = (float*)UB;                      // 512*9*4 = 18432 < 19584

    // ---- table loads ----
    if (tid < 256) q_sb[tid] = ws_q[b * 256 + tid];
    if (tid < 36) {
        if (tid < 18) n0_s[tid] = ws_n01[b * 36 + tid];
        else          n1_s[tid - 18] = ws_n01[b * 36 + tid];
    }
    if (tid < 312) {
        const int iy = tid / 26;
        lutxy[tid] = (unsigned int)(tid - iy * 26) | ((unsigned int)iy << 16);
    }
    if (tid < 64) b2_s[tid] = cb2[tid];
    if (tid < 16) b3_s[tid] = cb3[tid];
    if (tid < 32) {                                  // CPB layer-1 weight table
        const int qdi = tid >> 3, kp = tid & 7;
        const int kk0 = 2 * kp, kk1 = 2 * kp + 1;
        const int kid0 = (kk0 < 8) ? (qdi * 8 + kk0) : (32 + qdi * 8 + kk0 - 8);
        const int kid1 = (kk1 < 8) ? (qdi * 8 + kk1) : (32 + qdi * 8 + kk1 - 8);
        w1p[qdi][kp][0] = cw1[kid0 * 2];
        w1p[qdi][kp][1] = cw1[kid0 * 2 + 1];
        w1p[qdi][kp][2] = cb1[kid0];
        w1p[qdi][kp][3] = cw1[kid1 * 2];
        w1p[qdi][kp][4] = cw1[kid1 * 2 + 1];
        w1p[qdi][kp][5] = cb1[kid1];
    }
    __syncthreads();

    // ---- F0/F1 log tables (from n0/n1) ----
    for (int u = tid; u < 684; u += 512) {
        if (u < 468) {
            const int ixv = u / 18, j = u - ixv * 18;
            const float p0 = (float)ixv * (2.0f / 11.0f) - 1.0f - n0_s[j];
            F0[u] = copysignf(__logf(1.0f + fabsf(p0)), p0);
        } else {
            const int u2 = u - 468;
            const int iyv = u2 / 18, j = u2 - iyv * 18;
            const float p1 = (float)iyv * (2.0f / 25.0f) - 1.0f - n1_s[j];
            F1[u2] = copysignf(__logf(1.0f + fabsf(p1)), p1);
        }
    }

    // ---- per-lane weight fragments ----
    uint4 W2f[4][2], W3f[2];
    {
        const float4* cw2_4 = (const float4*)cw2;
        #pragma unroll
        for (int mtl = 0; mtl < 4; ++mtl)
            #pragma unroll
            for (int ks = 0; ks < 2; ++ks) {
                const int base = (mtl * 16 + n) * 16 + ks * 8 + qd * 2;
                W2f[mtl][ks] = pack8(cw2_4[base], cw2_4[base + 1]);
            }
        const float4* cw3_4 = (const float4*)cw3;
        #pragma unroll
        for (int ks = 0; ks < 2; ++ks) {
            const int base = n * 16 + ks * 8 + qd * 2;
            W3f[ks] = pack8(cw3_4[base], cw3_4[base + 1]);
        }
    }

    // ---- Bk fragments from global ws_k: wave w -> heads 2w, 2w+1 ----
    uint4 BkU[2][2];
    #pragma unroll
    for (int hh = 0; hh < 2; ++hh)
        #pragma unroll
        for (int jt = 0; jt < 2; ++jt) {
            unsigned int u0 = 0, u1 = 0, u2 = 0, u3 = 0;
            if (qd < 2 && (jt == 0 || n < 2)) {
                const int h = w * 2 + hh;
                const int j = jt * 16 + n;
                const unsigned short* kb = ws_k + b * 4608 + (h * 16 + qd * 8) * 18 + j;
                u0 = (unsigned)kb[0]   | ((unsigned)kb[18]  << 16);
                u1 = (unsigned)kb[36]  | ((unsigned)kb[54]  << 16);
                u2 = (unsigned)kb[72]  | ((unsigned)kb[90]  << 16);
                u3 = (unsigned)kb[108] | ((unsigned)kb[126] << 16);
            }
            BkU[hh][jt] = make_uint4(u0, u1, u2, u3);
        }
    __syncthreads();

    // ---- pipelined chunk loop: 10 chunks of 16 i's (last 12) ----
    float wAcc[9];
    #pragma unroll
    for (int jl = 0; jl < 9; ++jl) wAcc[jl] = 0.f;

    auto soft_acc = [&](int chp, const float* Sp) {
        const int h = tid & 15, hf = (tid >> 4) & 1, il = tid >> 5;   // il 0..15
        const int CIp = (chp == 9) ? 12 : 16;
        if (il < CIp) {                                   // wave-uniform
            const float cwv = conv_w[g * 156 + chp * 16 + il];
            float lv[9];
            const float* row = Sp + (il * 18 + hf * 9) * 17 + h;
            #pragma unroll
            for (int jl = 0; jl < 9; ++jl) lv[jl] = row[jl * 17];
            float m = lv[0];
            #pragma unroll
            for (int jl = 1; jl < 9; ++jl) m = fmaxf(m, lv[jl]);
            m = fmaxf(m, __shfl_xor(m, 16, 64));
            float s = 0.f;
            #pragma unroll
            for (int jl = 0; jl < 9; ++jl) { lv[jl] = __expf(lv[jl] - m); s += lv[jl]; }
            s += __shfl_xor(s, 16, 64);
            const float wgt = cwv / s;
            #pragma unroll
            for (int jl = 0; jl < 9; ++jl) wAcc[jl] = fmaf(wgt, lv[jl], wAcc[jl]);
        }
    };

    for (int ch = 0; ch < 10; ++ch) {
        float* Sc = Sbuf + (ch & 1) * 4896;
        const float* Sp = Sbuf + ((ch & 1) ^ 1) * 4896;
        const int ibase = g * 156 + ch * 16;

        // (a) sim: wave w -> heads 2w, 2w+1; 1 i-group x 2 j-tiles
        #pragma unroll
        for (int hh = 0; hh < 2; ++hh) {
            const int h = w * 2 + hh;
            const int base = h * 16 + qd * 8;
            unsigned int a0 = 0, a1 = 0, a2 = 0, a3u = 0;
            if (qd < 2) {
                const int ii = ibase + n;
                a0 = (unsigned)q_sb[((base + 0) * 56 + ii) & 255] |
                     ((unsigned)q_sb[((base + 1) * 56 + ii) & 255] << 16);
                a1 = (unsigned)q_sb[((base + 2) * 56 + ii) & 255] |
                     ((unsigned)q_sb[((base + 3) * 56 + ii) & 255] << 16);
                a2 = (unsigned)q_sb[((base + 4) * 56 + ii) & 255] |
                     ((unsigned)q_sb[((base + 5) * 56 + ii) & 255] << 16);
                a3u = (unsigned)q_sb[((base + 6) * 56 + ii) & 255] |
                      ((unsigned)q_sb[((base + 7) * 56 + ii) & 255] << 16);
            }
            U16 Af; Af.u = make_uint4(a0, a1, a2, a3u);
            #pragma unroll
            for (int jt = 0; jt < 2; ++jt) {
                U16 Bf; Bf.u = BkU[hh][jt];
                floatx4 D = {0.f, 0.f, 0.f, 0.f};
                D = MFMA(Af.s, Bf.s, D);
                const int j = jt * 16 + n;
                if (j < 18) {
                    #pragma unroll
                    for (int r = 0; r < 4; ++r)
                        Sc[((qd * 4 + r) * 18 + j) * 17 + h] = D[r];
                }
            }
        }
        // (c of ch-1) overlapped with (a): different buffer
        if (ch > 0) soft_acc(ch - 1, Sp);
        __syncthreads();

        // (b) CPB MLP + logits; 18 tiles over 8 waves
        {
            auto mlp1 = [&](int j) {
                const int i0 = ibase + n;
                const unsigned int lv2 = lutxy[(i0 < 312) ? i0 : 311];
                const int ix = (int)(lv2 & 0xffffu), iy = (int)(lv2 >> 16);
                const float f0 = F0[ix * 18 + j];
                const float f1 = F1[iy * 18 + j];
                U16 ub0, ub1;
                {
                    unsigned int uu[8];
                    #pragma unroll
                    for (int kp = 0; kp < 8; ++kp) {
                        const float* wp = &w1p[qd][kp][0];
                        const float ha = fmaxf(fmaf(wp[0], f0, fmaf(wp[1], f1, wp[2])), 0.f);
                        const float hb = fmaxf(fmaf(wp[3], f0, fmaf(wp[4], f1, wp[5])), 0.f);
                        uu[kp] = pk2(ha, hb);
                    }
                    ub0.u = make_uint4(uu[0], uu[1], uu[2], uu[3]);
                    ub1.u = make_uint4(uu[4], uu[5], uu[6], uu[7]);
                }
                // GEMM2 -> h2 to this wave's LDS region
                unsigned int* hw = h2w + w * 544 + n * 34;
                #pragma unroll
                for (int mtl = 0; mtl < 4; ++mtl) {
                    U16 A0, A1; A0.u = W2f[mtl][0]; A1.u = W2f[mtl][1];
                    floatx4 acc = {0.f, 0.f, 0.f, 0.f};
                    acc = MFMA(A0.s, ub0.s, acc);
                    acc = MFMA(A1.s, ub1.s, acc);
                    const float e0 = fmaxf(acc[0] + b2_s[mtl*16 + qd*4 + 0], 0.f);
                    const float e1 = fmaxf(acc[1] + b2_s[mtl*16 + qd*4 + 1], 0.f);
                    const float e2 = fmaxf(acc[2] + b2_s[mtl*16 + qd*4 + 2], 0.f);
                    const float e3 = fmaxf(acc[3] + b2_s[mtl*16 + qd*4 + 3], 0.f);
                    hw[mtl * 8 + qd * 2]     = pk2(e0, e1);
                    hw[mtl * 8 + qd * 2 + 1] = pk2(e2, e3);
                }
                // GEMM3 (compiler inserts the wave-local lgkm drain)
                const unsigned int* hwr = h2w + w * 544;
                U16 uc0, uc1;
                uc0.u = *(const uint4*)(hwr + n * 34 + qd * 4);
                uc1.u = *(const uint4*)(hwr + n * 34 + 16 + qd * 4);
                U16 A0, A1; A0.u = W3f[0]; A1.u = W3f[1];
                floatx4 a3 = {0.f, 0.f, 0.f, 0.f};
                a3 = MFMA(A0.s, uc0.s, a3);
                a3 = MFMA(A1.s, uc1.s, a3);
                float* sp = Sc + (n * 18 + j) * 17 + qd * 4;
                #pragma unroll
                for (int r = 0; r < 4; ++r) sp[r] = a3[r] + b3_s[qd * 4 + r] + sp[r];
            };
            mlp1(w);
            mlp1(w + 8);
            if (w < 2) mlp1(16 + w);
        }
        __syncthreads();
    }
    // drain: softmax for final chunk (buffer 9&1 = 1)
    soft_acc(9, Sbuf + 4896);

    // ---- reduce wAcc over 16 il-slots -> ws_wa[(b,g)][288] ----
    #pragma unroll
    for (int jl = 0; jl < 9; ++jl) wred[tid * 9 + jl] = wAcc[jl];
    __syncthreads();
    if (tid < 288) {
        const int h = tid / 18, j2 = tid - h * 18;
        const int hf = (j2 >= 9) ? 1 : 0, jl = j2 - hf * 9;
        float s = 0.f;
        #pragma unroll
        for (int sl = 0; sl < 16; ++sl) s += wred[(sl * 32 + hf * 16 + h) * 9 + jl];
        ws_wa[(b * 2 + g) * 288 + tid] = s;
    }
}

// ===========================================================================
// Kernel 3: tail — m, pooled, residual + LayerNorm
// ===========================================================================
__global__ __launch_bounds__(256, 2) void k_tail(
    const float* __restrict__ q, const float* __restrict__ w_out,
    const float* __restrict__ b_out, const float* __restrict__ conv_w,
    const float* __restrict__ conv_b, const float* __restrict__ ln_g,
    const float* __restrict__ ln_b,
    const unsigned short* __restrict__ ws_v, const float* __restrict__ ws_wa,
    float* __restrict__ out)
{
    const int b = blockIdx.x, tid = threadIdx.x;   // 256 threads
    const int w = tid >> 6, lane = tid & 63;

    __shared__ float wA_s[288];
    __shared__ __align__(16) float m_s[256];
    __shared__ float pooled_s[256], redb[12];

    for (int u = tid; u < 288; u += 256)
        wA_s[u] = ws_wa[(b * 2) * 288 + u] + ws_wa[(b * 2 + 1) * 288 + u];
    {
        float v = conv_w[tid];
        if (tid < 56) v += conv_w[256 + tid];
        for (int d = 32; d > 0; d >>= 1) v += __shfl_down(v, d, 64);
        if (lane == 0) redb[w] = v;
    }
    __syncthreads();

    // m[c] = sum_j wA[h(c)][j] * v[c][j]
    {
        const int hb = (tid >> 4) * 18;
        const unsigned short* vb = ws_v + b * 4608 + tid * 18;
        float acc = 0.f;
        #pragma unroll
        for (int j = 0; j < 18; ++j) acc += wA_s[hb + j] * bf2f(vb[j]);
        m_s[tid] = acc;
    }
    __syncthreads();

    const float Ssum = redb[0] + redb[1] + redb[2] + redb[3];

    // pooled = w_out . m  (4 waves x 64 rows, coalesced float4)
    {
        const float4 mm = *(const float4*)(m_s + lane * 4);
        for (int ol = 0; ol < 64; ++ol) {
            const int o = w * 64 + ol;
            const float4 wq = *(const float4*)(w_out + o * 256 + lane * 4);
            float d = wq.x * mm.x + wq.y * mm.y + wq.z * mm.z + wq.w * mm.w;
            for (int dd = 32; dd > 0; dd >>= 1) d += __shfl_down(d, dd, 64);
            if (lane == 0) pooled_s[o] = d;
        }
    }
    __syncthreads();

    // residual + LayerNorm
    const float y = pooled_s[tid] + b_out[tid] * Ssum + conv_b[0] + q[b * 256 + tid];
    float s1 = y, s2 = y * y;
    for (int d = 32; d > 0; d >>= 1) { s1 += __shfl_down(s1, d, 64); s2 += __shfl_down(s2, d, 64); }
    if (lane == 0) { redb[4 + w] = s1; redb[8 + w] = s2; }
    __syncthreads();
    const float S1 = redb[4] + redb[5] + redb[6] + redb[7];
    const float S2 = redb[8] + redb[9] + redb[10] + redb[11];
    const float mu = S1 * (1.0f / 256.0f);
    const float var = S2 * (1.0f / 256.0f) - mu * mu;
    out[b * 256 + tid] = (y - mu) * rsqrtf(var + 1e-5f) * ln_g[tid] + ln_b[tid];
}

// ===========================================================================
extern "C" void kernel_launch(void* const* d_in, const int* in_sizes, int n_in,
                              void* d_out, int out_size, void* d_ws, size_t ws_size,
                              hipStream_t stream) {
    const float* x       = (const float*)d_in[0];
    const float* q       = (const float*)d_in[1];
    const float* w_dw    = (const float*)d_in[2];
    const float* b_dwp   = (const float*)d_in[3];
    const float* w_pw    = (const float*)d_in[4];
    const float* wk      = (const float*)d_in[5];
    const float* wv      = (const float*)d_in[6];
    const float* w_out   = (const float*)d_in[7];
    const float* b_out   = (const float*)d_in[8];
    const float* cw1     = (const float*)d_in[9];
    const float* cb1     = (const float*)d_in[10];
    const float* cw2     = (const float*)d_in[11];
    const float* cb2     = (const float*)d_in[12];
    const float* cw3     = (const float*)d_in[13];
    const float* cb3     = (const float*)d_in[14];
    const float* conv_w  = (const float*)d_in[15];
    const float* conv_b  = (const float*)d_in[16];
    const float* ln_g    = (const float*)d_in[17];
    const float* ln_b    = (const float*)d_in[18];
    float* out = (float*)d_out;

    // workspace layout (5,476,352 B total)
    char* wsb = (char*)d_ws;
    unsigned short* ws_q   = (unsigned short*)(wsb);                         // 131072
    unsigned short* ws_k   = (unsigned short*)(wsb + 131072);                // 2359296
    unsigned short* ws_v   = (unsigned short*)(wsb + 131072 + 2359296);      // 2359296
    float*          ws_n01 = (float*)(wsb + 131072 + 2 * 2359296);           // 36864
    float*          ws_wa  = (float*)(wsb + 131072 + 2 * 2359296 + 36864);   // 589824

    k_setup<<<256, 512, 0, stream>>>(x, q, w_dw, b_dwp, w_pw, wk, wv,
                                     ws_q, ws_k, ws_v, ws_n01);
    k_chunks<<<512, 512, 0, stream>>>(cw1, cb1, cw2, cb2, cw3, cb3, conv_w,
                                      ws_q, ws_k, ws_n01, ws_wa);
    k_tail<<<256, 256, 0, stream>>>(q, w_out, b_out, conv_w, conv_b,
                                    ln_g, ln_b, ws_v, ws_wa, out);
}

// Round 6
// 301.055 us; speedup vs baseline: 1.4496x; 1.4496x over previous
//
#include <hip/hip_runtime.h>
#include <hip/hip_bf16.h>
#include <math.h>

// ---------------------------------------------------------------------------
// DIM=256 HEADS=16 DHEAD=16 H=12 W=26 (HW=312)  Hk=3 Wk=6 (J=18)  B=256
// q_map[b,c,s] = q[b,(c*56+s)&255]
// Round 13: r12 split, k_chunks reverted to the PROVEN codegen shape.
// Allocator evidence (r7..r12): only LB(512,2) yields a sane allocation
// (120 regs, no spill); every other bound/shape targets 6-8 waves/EU
// (64/84 regs) and spills ~0.5-1.7KB/thread (r12: 700MB HBM traffic).
// 120 regs x 16 waves = 1920 <= 2048 pool, k_chunks LDS 63KB -> 2 blocks/CU
// = 16 waves/CU via LB(512,2) WITHOUT asking the allocator for anything.
// Diffs vs r12: k_chunks LB(512,4)->(512,2); soft_acc back to r7 full-row
// lv[18] form (tid<256, no shfl) -- the register profile that worked.
// ---------------------------------------------------------------------------

typedef __attribute__((ext_vector_type(8))) short short8;   // 8 bf16
typedef __attribute__((ext_vector_type(4))) float floatx4;

union U16 { uint4 u; short8 s; };

#define MFMA(A, B, C) __builtin_amdgcn_mfma_f32_16x16x32_bf16((A), (B), (C), 0, 0, 0)

__device__ __forceinline__ unsigned int f2bf(float f) {   // RNE f32->bf16 (low 16)
    unsigned int u = __float_as_uint(f);
    u += 0x7fffu + ((u >> 16) & 1u);
    return u >> 16;
}
__device__ __forceinline__ unsigned int pk2(float a, float b) {   // HW cvt_pk
    __hip_bfloat162 h = __float22bfloat162_rn(make_float2(a, b));
    union { __hip_bfloat162 h; unsigned int u; } cv; cv.h = h;
    return cv.u;
}
__device__ __forceinline__ float bf2f(unsigned short v) {
    return __uint_as_float((unsigned int)v << 16);
}
__device__ __forceinline__ uint4 pack8(float4 a, float4 b) {
    uint4 r;
    r.x = pk2(a.x, a.y); r.y = pk2(a.z, a.w);
    r.z = pk2(b.x, b.y); r.w = pk2(b.z, b.w);
    return r;
}

// ===========================================================================
// Kernel 1: setup (r7-verbatim phases) + export to workspace
// ===========================================================================
__global__ __launch_bounds__(512, 2) void k_setup(
    const float* __restrict__ x, const float* __restrict__ q,
    const float* __restrict__ w_dw, const float* __restrict__ b_dw,
    const float* __restrict__ w_pw,
    const float* __restrict__ wk, const float* __restrict__ wv,
    unsigned short* __restrict__ ws_q, unsigned short* __restrict__ ws_k,
    unsigned short* __restrict__ ws_v, float* __restrict__ ws_n01)
{
    const int b = blockIdx.x, tid = threadIdx.x;
    const int w = tid >> 6, lane = tid & 63;
    const int n = lane & 15, qd = lane >> 4;

    __shared__ unsigned short q_sb[256];
    __shared__ unsigned short v_sb[5120];           // [256][20]
    __shared__ float off_s[36], n0_s[18], n1_s[18];
    __shared__ float sx0[18], sy0[18], swx[18], swy[18];
    __shared__ __align__(16) unsigned char UB[34944];
    float* qsw = (float*)UB;                         // 4128 f (16 x 258)
    unsigned short* kvT = (unsigned short*)UB;       // [18][264] aliases qsw
    float* t_s = (float*)(UB + 16512);               // [18][256]
    unsigned short* k_sb = (unsigned short*)(UB + 16512);  // [256][20] aliases t_s

    // ---- stage 0 ----
    if (tid < 256) {
        const float qv = q[b * 256 + tid];
        const unsigned short qb = (unsigned short)f2bf(qv * 0.25f);
        q_sb[tid] = qb;
        ws_q[b * 256 + tid] = qb;
    }
    for (int u = tid; u < 4128; u += 512) {
        const int r = u / 258, i = u - r * 258;
        qsw[u] = (i < 256) ? q[b * 256 + i] : 0.f;
    }
    __syncthreads();

    // ---- depthwise conv 6x6 s4 p1 + GELU -> t_s ----
    {
        const int c = tid & 255, g = tid >> 8;     // g: jw-half
        float wreg[36];
        const float4* wdw4 = (const float4*)w_dw;  // [c][36] contiguous
        #pragma unroll
        for (int i = 0; i < 9; ++i) {
            const float4 t4 = wdw4[c * 9 + i];
            wreg[i * 4 + 0] = t4.x; wreg[i * 4 + 1] = t4.y;
            wreg[i * 4 + 2] = t4.z; wreg[i * 4 + 3] = t4.w;
        }
        float acc[9];
        const float bv = b_dw[c];
        #pragma unroll
        for (int a = 0; a < 9; ++a) acc[a] = bv;
        const int cb = (c * 56) & 255;
        const int cp = (c & 15) * 258;
        for (int jh = 0; jh < 3; ++jh) {
            for (int kh = 0; kh < 6; ++kh) {
                const int ih = jh * 4 - 1 + kh;
                if (ih < 0 || ih >= 12) continue;
                const int rb = ih * 26;
                #pragma unroll
                for (int jwl = 0; jwl < 3; ++jwl) {
                    const int jw = g * 3 + jwl;
                    #pragma unroll
                    for (int kw = 0; kw < 6; ++kw) {
                        const int iw = jw * 4 - 1 + kw;
                        if (iw < 0 || iw >= 26) continue;
                        acc[jh * 3 + jwl] += wreg[kh * 6 + kw] * qsw[cp + ((cb + rb + iw) & 255)];
                    }
                }
            }
        }
        #pragma unroll
        for (int a = 0; a < 9; ++a) {
            const int jh = a / 3, jwl = a - jh * 3;
            const int p = jh * 6 + g * 3 + jwl;
            const float v = acc[a];
            t_s[p * 256 + c] = 0.5f * v * (1.0f + erff(v * 0.70710678118654752f));
        }
    }
    __syncthreads();

    // ---- offsets: 36 dots over 256 channels ----
    for (int oi = w; oi < 36; oi += 8) {
        const int o = oi / 18, p = oi - o * 18;
        float s = 0.f;
        for (int c = lane; c < 256; c += 64) s += w_pw[o * 256 + c] * t_s[p * 256 + c];
        for (int d = 32; d > 0; d >>= 1) s += __shfl_down(s, d, 64);
        if (lane == 0) off_s[oi] = 4.0f * tanhf(s);
    }
    __syncthreads();

    // ---- grid coords + bilinear params (+ n0/n1 export) ----
    if (tid < 18) {
        const int j = tid, jh = j / 6, jw = j - jh * 6;
        const float vg0 = (float)jw + off_s[j];
        const float vg1 = (float)jh + off_s[18 + j];
        const float n0 = 2.0f * vg0 / 2.0f - 1.0f;
        const float n1 = 2.0f * vg1 / 5.0f - 1.0f;
        n0_s[j] = n0; n1_s[j] = n1;
        ws_n01[b * 36 + j] = n0;
        ws_n01[b * 36 + 18 + j] = n1;
        const float xp = ((n0 + 1.0f) * 26.0f - 1.0f) * 0.5f;
        const float yp = ((n1 + 1.0f) * 12.0f - 1.0f) * 0.5f;
        const float x0 = floorf(xp), y0 = floorf(yp);
        sx0[j] = x0; sy0[j] = y0; swx[j] = xp - x0; swy[j] = yp - y0;
    }
    __syncthreads();

    // ---- bilinear sample -> kvT bf16 [j][264] (qsw region dead) ----
    {
        const int c = tid & 255, g = tid >> 8;
        const float* xb = x + ((size_t)b * 256 + c) * 312;
        for (int jj = 0; jj < 9; ++jj) {
            const int j = g * 9 + jj;
            const int x0 = (int)sx0[j], y0 = (int)sy0[j];
            const int x1 = x0 + 1, y1 = y0 + 1;
            const float wx1 = swx[j], wy1 = swy[j];
            const float wx0 = 1.f - wx1, wy0 = 1.f - wy1;
            const bool xv0 = (x0 >= 0) & (x0 < 26), xv1 = (x1 >= 0) & (x1 < 26);
            const bool yv0 = (y0 >= 0) & (y0 < 12), yv1 = (y1 >= 0) & (y1 < 12);
            const float v00 = (xv0 & yv0) ? xb[y0 * 26 + x0] : 0.f;
            const float v01 = (xv1 & yv0) ? xb[y0 * 26 + x1] : 0.f;
            const float v10 = (xv0 & yv1) ? xb[y1 * 26 + x0] : 0.f;
            const float v11 = (xv1 & yv1) ? xb[y1 * 26 + x1] : 0.f;
            const float val = wy0 * (wx0 * v00 + wx1 * v01) + wy1 * (wx0 * v10 + wx1 * v11);
            kvT[j * 264 + c] = (unsigned short)f2bf(val);
        }
    }
    __syncthreads();

    // ---- k/v projection via MFMA: wave w -> matrix (w&1), mtb = w>>1 ----
    {
        const int m2 = w & 1, mtb = w >> 1;
        const float4* wm4 = (const float4*)(m2 ? wv : wk);
        floatx4 pa[4][2];
        #pragma unroll
        for (int a = 0; a < 4; ++a) {
            pa[a][0] = (floatx4){0.f, 0.f, 0.f, 0.f};
            pa[a][1] = (floatx4){0.f, 0.f, 0.f, 0.f};
        }
        #pragma unroll 2
        for (int ks = 0; ks < 8; ++ks) {
            U16 b0, b1;
            b0.u = *(const uint4*)(kvT + n * 264 + ks * 32 + qd * 8);
            b1.u = make_uint4(0u, 0u, 0u, 0u);
            if (n < 2) b1.u = *(const uint4*)(kvT + (16 + n) * 264 + ks * 32 + qd * 8);
            #pragma unroll
            for (int mtl = 0; mtl < 4; ++mtl) {
                const int mt = mtb + mtl * 4;
                const int f4i = (mt * 16 + n) * 64 + ks * 8 + qd * 2;
                U16 A; A.u = pack8(wm4[f4i], wm4[f4i + 1]);
                pa[mtl][0] = MFMA(A.s, b0.s, pa[mtl][0]);
                pa[mtl][1] = MFMA(A.s, b1.s, pa[mtl][1]);
            }
        }
        unsigned short* dst = m2 ? v_sb : k_sb;
        #pragma unroll
        for (int mtl = 0; mtl < 4; ++mtl) {
            const int mt = mtb + mtl * 4;
            #pragma unroll
            for (int r = 0; r < 4; ++r) {
                const int o = mt * 16 + qd * 4 + r;
                dst[o * 20 + n] = (unsigned short)f2bf(pa[mtl][0][r]);
                if (n < 2) dst[o * 20 + 16 + n] = (unsigned short)f2bf(pa[mtl][1][r]);
            }
        }
    }
    __syncthreads();

    // ---- export k, v as [256][18] bf16 ----
    for (int u = tid; u < 4608; u += 512) {
        const int c = u / 18, j = u - c * 18;
        ws_k[b * 4608 + u] = k_sb[c * 20 + j];
        ws_v[b * 4608 + u] = v_sb[c * 20 + j];
    }
}

// ===========================================================================
// Kernel 2: chunk loop. Block (b,g): i in [g*156, g*156+156), 10 chunks of 16
// LB(512,2): the only allocator-sane shape (r7 evidence). LDS 63KB ->
// 2 blocks/CU resident (120reg x 16w = 1920 <= 2048 pool).
// ===========================================================================
__global__ __launch_bounds__(512, 2) void k_chunks(
    const float* __restrict__ cw1, const float* __restrict__ cb1,
    const float* __restrict__ cw2, const float* __restrict__ cb2,
    const float* __restrict__ cw3, const float* __restrict__ cb3,
    const float* __restrict__ conv_w,
    const unsigned short* __restrict__ ws_q, const unsigned short* __restrict__ ws_k,
    const float* __restrict__ ws_n01, float* __restrict__ ws_wa)
{
    const int bb = blockIdx.x;                     // 0..511
    const int b = bb >> 1, g = bb & 1;
    const int tid = threadIdx.x;
    const int w = tid >> 6, lane = tid & 63;       // w in 0..7
    const int n = lane & 15, qd = lane >> 4;

    __shared__ unsigned short q_sb[256];
    __shared__ float F0[468], F1[216];
    __shared__ float n0_s[18], n1_s[18];
    __shared__ unsigned int lutxy[312];
    __shared__ float b2_s[64], b3_s[16];
    __shared__ __align__(16) float w1p[4][8][8];
    // S double buffer 2 x [16 il][18 j][17 h] f32 = 39168 B; h2w 8x544 uints
    __shared__ __align__(16) unsigned char UB[56576];
    float* Sbuf = (float*)UB;
    unsigned int* h2w = (unsigned int*)(UB + 39168);
    float* wred = (float*)UB;                      // 256*18*4 = 18432 < 19584

    // ---- table loads ----
    if (tid < 256) q_sb[tid] = ws_q[b * 256 + tid];
    if (tid < 36) {
        if (tid < 18) n0_s[tid] = ws_n01[b * 36 + tid];
        else          n1_s[tid - 18] = ws_n01[b * 36 + tid];
    }
    if (tid < 312) {
        const int iy = tid / 26;
        lutxy[tid] = (unsigned int)(tid - iy * 26) | ((unsigned int)iy << 16);
    }
    if (tid < 64) b2_s[tid] = cb2[tid];
    if (tid < 16) b3_s[tid] = cb3[tid];
    if (tid < 32) {                                  // CPB layer-1 weight table
        const int qdi = tid >> 3, kp = tid & 7;
        const int kk0 = 2 * kp, kk1 = 2 * kp + 1;
        const int kid0 = (kk0 < 8) ? (qdi * 8 + kk0) : (32 + qdi * 8 + kk0 - 8);
        const int kid1 = (kk1 < 8) ? (qdi * 8 + kk1) : (32 + qdi * 8 + kk1 - 8);
        w1p[qdi][kp][0] = cw1[kid0 * 2];
        w1p[qdi][kp][1] = cw1[kid0 * 2 + 1];
        w1p[qdi][kp][2] = cb1[kid0];
        w1p[qdi][kp][3] = cw1[kid1 * 2];
        w1p[qdi][kp][4] = cw1[kid1 * 2 + 1];
        w1p[qdi][kp][5] = cb1[kid1];
    }
    __syncthreads();

    // ---- F0/F1 log tables (from n0/n1) ----
    for (int u = tid; u < 684; u += 512) {
        if (u < 468) {
            const int ixv = u / 18, j = u - ixv * 18;
            const float p0 = (float)ixv * (2.0f / 11.0f) - 1.0f - n0_s[j];
            F0[u] = copysignf(__logf(1.0f + fabsf(p0)), p0);
        } else {
            const int u2 = u - 468;
            const int iyv = u2 / 18, j = u2 - iyv * 18;
            const float p1 = (float)iyv * (2.0f / 25.0f) - 1.0f - n1_s[j];
            F1[u2] = copysignf(__logf(1.0f + fabsf(p1)), p1);
        }
    }

    // ---- per-lane weight fragments ----
    uint4 W2f[4][2], W3f[2];
    {
        const float4* cw2_4 = (const float4*)cw2;
        #pragma unroll
        for (int mtl = 0; mtl < 4; ++mtl)
            #pragma unroll
            for (int ks = 0; ks < 2; ++ks) {
                const int base = (mtl * 16 + n) * 16 + ks * 8 + qd * 2;
                W2f[mtl][ks] = pack8(cw2_4[base], cw2_4[base + 1]);
            }
        const float4* cw3_4 = (const float4*)cw3;
        #pragma unroll
        for (int ks = 0; ks < 2; ++ks) {
            const int base = n * 16 + ks * 8 + qd * 2;
            W3f[ks] = pack8(cw3_4[base], cw3_4[base + 1]);
        }
    }

    // ---- Bk fragments from global ws_k: wave w -> heads 2w, 2w+1 ----
    uint4 BkU[2][2];
    #pragma unroll
    for (int hh = 0; hh < 2; ++hh)
        #pragma unroll
        for (int jt = 0; jt < 2; ++jt) {
            unsigned int u0 = 0, u1 = 0, u2 = 0, u3 = 0;
            if (qd < 2 && (jt == 0 || n < 2)) {
                const int h = w * 2 + hh;
                const int j = jt * 16 + n;
                const unsigned short* kb = ws_k + b * 4608 + (h * 16 + qd * 8) * 18 + j;
                u0 = (unsigned)kb[0]   | ((unsigned)kb[18]  << 16);
                u1 = (unsigned)kb[36]  | ((unsigned)kb[54]  << 16);
                u2 = (unsigned)kb[72]  | ((unsigned)kb[90]  << 16);
                u3 = (unsigned)kb[108] | ((unsigned)kb[126] << 16);
            }
            BkU[hh][jt] = make_uint4(u0, u1, u2, u3);
        }
    __syncthreads();

    // ---- pipelined chunk loop: 10 chunks of 16 i's (last 12) ----
    float wAcc[18];
    #pragma unroll
    for (int j = 0; j < 18; ++j) wAcc[j] = 0.f;

    // r7-style full-row softmax: threads 0..255, il = tid>>4, h = tid&15
    auto soft_acc = [&](int chp, const float* Sp) {
        if (tid < 256) {
            const int il = tid >> 4, h = tid & 15;
            const int CIp = (chp == 9) ? 12 : 16;
            if (il < CIp) {
                const float cwv = conv_w[g * 156 + chp * 16 + il];
                float lv[18];
                const float* row = Sp + (il * 18) * 17 + h;
                #pragma unroll
                for (int j = 0; j < 18; ++j) lv[j] = row[j * 17];
                float m = lv[0];
                #pragma unroll
                for (int j = 1; j < 18; ++j) m = fmaxf(m, lv[j]);
                float s = 0.f;
                #pragma unroll
                for (int j = 0; j < 18; ++j) { lv[j] = __expf(lv[j] - m); s += lv[j]; }
                const float wgt = cwv / s;
                #pragma unroll
                for (int j = 0; j < 18; ++j) wAcc[j] = fmaf(wgt, lv[j], wAcc[j]);
            }
        }
    };

    for (int ch = 0; ch < 10; ++ch) {
        float* Sc = Sbuf + (ch & 1) * 4896;
        const float* Sp = Sbuf + ((ch & 1) ^ 1) * 4896;
        const int ibase = g * 156 + ch * 16;

        // (a) sim: wave w -> heads 2w, 2w+1; 1 i-group x 2 j-tiles
        #pragma unroll
        for (int hh = 0; hh < 2; ++hh) {
            const int h = w * 2 + hh;
            const int base = h * 16 + qd * 8;
            unsigned int a0 = 0, a1 = 0, a2 = 0, a3u = 0;
            if (qd < 2) {
                const int ii = ibase + n;
                a0 = (unsigned)q_sb[((base + 0) * 56 + ii) & 255] |
                     ((unsigned)q_sb[((base + 1) * 56 + ii) & 255] << 16);
                a1 = (unsigned)q_sb[((base + 2) * 56 + ii) & 255] |
                     ((unsigned)q_sb[((base + 3) * 56 + ii) & 255] << 16);
                a2 = (unsigned)q_sb[((base + 4) * 56 + ii) & 255] |
                     ((unsigned)q_sb[((base + 5) * 56 + ii) & 255] << 16);
                a3u = (unsigned)q_sb[((base + 6) * 56 + ii) & 255] |
                      ((unsigned)q_sb[((base + 7) * 56 + ii) & 255] << 16);
            }
            U16 Af; Af.u = make_uint4(a0, a1, a2, a3u);
            #pragma unroll
            for (int jt = 0; jt < 2; ++jt) {
                U16 Bf; Bf.u = BkU[hh][jt];
                floatx4 D = {0.f, 0.f, 0.f, 0.f};
                D = MFMA(Af.s, Bf.s, D);
                const int j = jt * 16 + n;
                if (j < 18) {
                    #pragma unroll
                    for (int r = 0; r < 4; ++r)
                        Sc[((qd * 4 + r) * 18 + j) * 17 + h] = D[r];
                }
            }
        }
        // (c of ch-1) overlapped with (a): different buffer
        if (ch > 0) soft_acc(ch - 1, Sp);
        __syncthreads();

        // (b) CPB MLP + logits; 18 tiles over 8 waves
        {
            auto mlp1 = [&](int j) {
                const int i0 = ibase + n;
                const unsigned int lv2 = lutxy[(i0 < 312) ? i0 : 311];
                const int ix = (int)(lv2 & 0xffffu), iy = (int)(lv2 >> 16);
                const float f0 = F0[ix * 18 + j];
                const float f1 = F1[iy * 18 + j];
                U16 ub0, ub1;
                {
                    unsigned int uu[8];
                    #pragma unroll
                    for (int kp = 0; kp < 8; ++kp) {
                        const float* wp = &w1p[qd][kp][0];
                        const float ha = fmaxf(fmaf(wp[0], f0, fmaf(wp[1], f1, wp[2])), 0.f);
                        const float hb = fmaxf(fmaf(wp[3], f0, fmaf(wp[4], f1, wp[5])), 0.f);
                        uu[kp] = pk2(ha, hb);
                    }
                    ub0.u = make_uint4(uu[0], uu[1], uu[2], uu[3]);
                    ub1.u = make_uint4(uu[4], uu[5], uu[6], uu[7]);
                }
                // GEMM2 -> h2 to this wave's LDS region
                unsigned int* hw = h2w + w * 544 + n * 34;
                #pragma unroll
                for (int mtl = 0; mtl < 4; ++mtl) {
                    U16 A0, A1; A0.u = W2f[mtl][0]; A1.u = W2f[mtl][1];
                    floatx4 acc = {0.f, 0.f, 0.f, 0.f};
                    acc = MFMA(A0.s, ub0.s, acc);
                    acc = MFMA(A1.s, ub1.s, acc);
                    const float e0 = fmaxf(acc[0] + b2_s[mtl*16 + qd*4 + 0], 0.f);
                    const float e1 = fmaxf(acc[1] + b2_s[mtl*16 + qd*4 + 1], 0.f);
                    const float e2 = fmaxf(acc[2] + b2_s[mtl*16 + qd*4 + 2], 0.f);
                    const float e3 = fmaxf(acc[3] + b2_s[mtl*16 + qd*4 + 3], 0.f);
                    hw[mtl * 8 + qd * 2]     = pk2(e0, e1);
                    hw[mtl * 8 + qd * 2 + 1] = pk2(e2, e3);
                }
                // GEMM3 (compiler inserts the wave-local lgkm drain)
                const unsigned int* hwr = h2w + w * 544;
                U16 uc0, uc1;
                uc0.u = *(const uint4*)(hwr + n * 34 + qd * 4);
                uc1.u = *(const uint4*)(hwr + n * 34 + 16 + qd * 4);
                U16 A0, A1; A0.u = W3f[0]; A1.u = W3f[1];
                floatx4 a3 = {0.f, 0.f, 0.f, 0.f};
                a3 = MFMA(A0.s, uc0.s, a3);
                a3 = MFMA(A1.s, uc1.s, a3);
                float* sp = Sc + (n * 18 + j) * 17 + qd * 4;
                #pragma unroll
                for (int r = 0; r < 4; ++r) sp[r] = a3[r] + b3_s[qd * 4 + r] + sp[r];
            };
            mlp1(w);
            mlp1(w + 8);
            if (w < 2) mlp1(16 + w);
        }
        __syncthreads();
    }
    // drain: softmax for final chunk (buffer 9&1 = 1)
    soft_acc(9, Sbuf + 4896);

    // ---- reduce wAcc over 16 il-slots -> ws_wa[(b,g)][288] ----
    // wred aliases S buffer 0 (18432B < 19584B); soft_acc(9) read buffer 1.
    if (tid < 256) {
        #pragma unroll
        for (int j = 0; j < 18; ++j) wred[tid * 18 + j] = wAcc[j];
    }
    __syncthreads();
    if (tid < 288) {
        const int h = tid / 18, j = tid - h * 18;
        float s = 0.f;
        #pragma unroll
        for (int sl = 0; sl < 16; ++sl) s += wred[(sl * 16 + h) * 18 + j];
        ws_wa[(b * 2 + g) * 288 + tid] = s;
    }
}

// ===========================================================================
// Kernel 3: tail — m, pooled, residual + LayerNorm
// ===========================================================================
__global__ __launch_bounds__(256, 2) void k_tail(
    const float* __restrict__ q, const float* __restrict__ w_out,
    const float* __restrict__ b_out, const float* __restrict__ conv_w,
    const float* __restrict__ conv_b, const float* __restrict__ ln_g,
    const float* __restrict__ ln_b,
    const unsigned short* __restrict__ ws_v, const float* __restrict__ ws_wa,
    float* __restrict__ out)
{
    const int b = blockIdx.x, tid = threadIdx.x;   // 256 threads
    const int w = tid >> 6, lane = tid & 63;

    __shared__ float wA_s[288];
    __shared__ __align__(16) float m_s[256];
    __shared__ float pooled_s[256], redb[12];

    for (int u = tid; u < 288; u += 256)
        wA_s[u] = ws_wa[(b * 2) * 288 + u] + ws_wa[(b * 2 + 1) * 288 + u];
    {
        float v = conv_w[tid];
        if (tid < 56) v += conv_w[256 + tid];
        for (int d = 32; d > 0; d >>= 1) v += __shfl_down(v, d, 64);
        if (lane == 0) redb[w] = v;
    }
    __syncthreads();

    // m[c] = sum_j wA[h(c)][j] * v[c][j]
    {
        const int hb = (tid >> 4) * 18;
        const unsigned short* vb = ws_v + b * 4608 + tid * 18;
        float acc = 0.f;
        #pragma unroll
        for (int j = 0; j < 18; ++j) acc += wA_s[hb + j] * bf2f(vb[j]);
        m_s[tid] = acc;
    }
    __syncthreads();

    const float Ssum = redb[0] + redb[1] + redb[2] + redb[3];

    // pooled = w_out . m  (4 waves x 64 rows, coalesced float4)
    {
        const float4 mm = *(const float4*)(m_s + lane * 4);
        for (int ol = 0; ol < 64; ++ol) {
            const int o = w * 64 + ol;
            const float4 wq = *(const float4*)(w_out + o * 256 + lane * 4);
            float d = wq.x * mm.x + wq.y * mm.y + wq.z * mm.z + wq.w * mm.w;
            for (int dd = 32; dd > 0; dd >>= 1) d += __shfl_down(d, dd, 64);
            if (lane == 0) pooled_s[o] = d;
        }
    }
    __syncthreads();

    // residual + LayerNorm
    const float y = pooled_s[tid] + b_out[tid] * Ssum + conv_b[0] + q[b * 256 + tid];
    float s1 = y, s2 = y * y;
    for (int d = 32; d > 0; d >>= 1) { s1 += __shfl_down(s1, d, 64); s2 += __shfl_down(s2, d, 64); }
    if (lane == 0) { redb[4 + w] = s1; redb[8 + w] = s2; }
    __syncthreads();
    const float S1 = redb[4] + redb[5] + redb[6] + redb[7];
    const float S2 = redb[8] + redb[9] + redb[10] + redb[11];
    const float mu = S1 * (1.0f / 256.0f);
    const float var = S2 * (1.0f / 256.0f) - mu * mu;
    out[b * 256 + tid] = (y - mu) * rsqrtf(var + 1e-5f) * ln_g[tid] + ln_b[tid];
}

// ===========================================================================
extern "C" void kernel_launch(void* const* d_in, const int* in_sizes, int n_in,
                              void* d_out, int out_size, void* d_ws, size_t ws_size,
                              hipStream_t stream) {
    const float* x       = (const float*)d_in[0];
    const float* q       = (const float*)d_in[1];
    const float* w_dw    = (const float*)d_in[2];
    const float* b_dwp   = (const float*)d_in[3];
    const float* w_pw    = (const float*)d_in[4];
    const float* wk      = (const float*)d_in[5];
    const float* wv      = (const float*)d_in[6];
    const float* w_out   = (const float*)d_in[7];
    const float* b_out   = (const float*)d_in[8];
    const float* cw1     = (const float*)d_in[9];
    const float* cb1     = (const float*)d_in[10];
    const float* cw2     = (const float*)d_in[11];
    const float* cb2     = (const float*)d_in[12];
    const float* cw3     = (const float*)d_in[13];
    const float* cb3     = (const float*)d_in[14];
    const float* conv_w  = (const float*)d_in[15];
    const float* conv_b  = (const float*)d_in[16];
    const float* ln_g    = (const float*)d_in[17];
    const float* ln_b    = (const float*)d_in[18];
    float* out = (float*)d_out;

    // workspace layout (5,476,352 B total)
    char* wsb = (char*)d_ws;
    unsigned short* ws_q   = (unsigned short*)(wsb);                         // 131072
    unsigned short* ws_k   = (unsigned short*)(wsb + 131072);                // 2359296
    unsigned short* ws_v   = (unsigned short*)(wsb + 131072 + 2359296);      // 2359296
    float*          ws_n01 = (float*)(wsb + 131072 + 2 * 2359296);           // 36864
    float*          ws_wa  = (float*)(wsb + 131072 + 2 * 2359296 + 36864);   // 589824

    k_setup<<<256, 512, 0, stream>>>(x, q, w_dw, b_dwp, w_pw, wk, wv,
                                     ws_q, ws_k, ws_v, ws_n01);
    k_chunks<<<512, 512, 0, stream>>>(cw1, cb1, cw2, cb2, cw3, cb3, conv_w,
                                      ws_q, ws_k, ws_n01, ws_wa);
    k_tail<<<256, 256, 0, stream>>>(q, w_out, b_out, conv_w, conv_b,
                                    ln_g, ln_b, ws_v, ws_wa, out);
}